// Round 1
// baseline (330.133 us; speedup 1.0000x reference)
//
#include <hip/hip_runtime.h>
#include <hip/hip_bf16.h>
#include <stdint.h>

// SoftTree: x(65536x512) f32, gw(512x255) f32, gb(255) f32, z(256x256) f32 -> out(65536x256) f32
// g = sigmoid(x@gw+gb); leaf = depth-8 tree products of g / (1-g); out = leaf @ z^T.
//
// This version: GEMM1 is fully barrier-free. A-frags (x) are loaded per-lane from global
// and cvt_pk'd to bf16 in registers; B-frags (gwt, L2-resident 256KB) are read straight
// from global like GEMM2 already does with zb. No LDS staging, no global_load_lds, so no
// vmcnt(0) drains — the compiler's counted waits + 16 waves/CU keep HBM loads in flight.
// LDS holds only the gates buffer (64x258 f32 = 66 KB -> 2 blocks/CU).

typedef short bf16x8 __attribute__((ext_vector_type(8)));
typedef float f32x4  __attribute__((ext_vector_type(4)));

__device__ __forceinline__ unsigned short f2bf(float f) {
    union { float f; uint32_t u; } c; c.f = f;
    uint32_t u = c.u;
    return (unsigned short)((u + 0x7FFFu + ((u >> 16) & 1u)) >> 16);
}

__device__ __forceinline__ uint32_t pkbf(float a, float b) {
    union { __hip_bfloat162 h; uint32_t u; } cv;
    cv.h = __float22bfloat162_rn(make_float2(a, b));   // v_cvt_pk_bf16_f32 on gfx950
    return cv.u;
}

// ---- prep: blocks 0..31 transpose gw (512x255 f32, gate-fast) -> gwt bf16 [gate][k] (256x512, row255=0)
//            blocks 32..95: z (256x256 f32) -> zb bf16
__global__ __launch_bounds__(256) void softtree_prep(
    const float* __restrict__ gw, const float* __restrict__ z,
    unsigned short* __restrict__ gwt, unsigned short* __restrict__ zb)
{
    if (blockIdx.x < 32) {
        __shared__ float tsm[64][65];
        const int k0 = (blockIdx.x >> 2) * 64;
        const int n0 = (blockIdx.x & 3) * 64;
        const int r = threadIdx.x >> 6;   // 0..3
        const int c = threadIdx.x & 63;   // 0..63
        const int n = n0 + c;
        #pragma unroll
        for (int i = 0; i < 16; ++i) {
            int kk = r + i * 4;
            tsm[kk][c] = (n < 255) ? gw[(size_t)(k0 + kk) * 255 + n] : 0.0f;
        }
        __syncthreads();
        #pragma unroll
        for (int i = 0; i < 16; ++i) {
            int nn = r + i * 4;           // local gate index
            gwt[(size_t)(n0 + nn) * 512 + k0 + c] = f2bf(tsm[c][nn]);
        }
    } else {
        int base = (blockIdx.x - 32) * 1024 + threadIdx.x * 4;
        const float4 v = *(const float4*)(z + base);
        ushort4 o;
        o.x = f2bf(v.x); o.y = f2bf(v.y); o.z = f2bf(v.z); o.w = f2bf(v.w);
        *(ushort4*)(zb + base) = o;
    }
}

// ---- main: 512 threads (8 waves), 2 row-tiles of 64 per block, grid 512.
// Wave (wr = wv&3, wc = wv>>2): rows 16*wr + l15 (both tiles), gates 128*wc + nt*16 + l15.
__global__ __launch_bounds__(512, 4) void softtree_main(
    const float* __restrict__ x, const float* __restrict__ gb,
    const unsigned short* __restrict__ gwt, const unsigned short* __restrict__ zb,
    float* __restrict__ out)
{
    __shared__ float gs[64 * 258];   // 66048 B: gates for one 64-row tile, stride 258

    const int tid  = threadIdx.x;
    const int lane = tid & 63;
    const int wv   = tid >> 6;
    const int q    = lane >> 4;
    const int l15  = lane & 15;
    const int wr   = wv & 3;
    const int wc   = wv >> 2;
    const int R0   = blockIdx.x * 128;

    // A-frag base: row = R0 + t*64 + 16*wr + l15, frag k-elems = kc*64 + 32*s + 8*q + j
    const float* xr = x + (size_t)(R0 + 16 * wr + l15) * 512 + 8 * q;
    // B-frag base: gate = 128*wc + nt*16 + l15, same k mapping (gwt is [gate][k] bf16)
    const unsigned short* bp = gwt + (size_t)(128 * wc + l15) * 512 + 8 * q;

    f32x4 acc[2][8];
    #pragma unroll
    for (int t = 0; t < 2; ++t)
        #pragma unroll
        for (int i = 0; i < 8; ++i) acc[t][i] = (f32x4){0.f, 0.f, 0.f, 0.f};

    // ---- GEMM1: barrier-free streaming K-loop (K=512, 32 per MFMA step)
    #pragma unroll 2
    for (int kc = 0; kc < 8; ++kc) {
        #pragma unroll
        for (int s = 0; s < 2; ++s) {
            const int ko = kc * 64 + 32 * s;
            bf16x8 a0, a1;
            {
                const float4 v0 = *(const float4*)(xr + ko);
                const float4 v1 = *(const float4*)(xr + ko + 4);
                union { bf16x8 v; uint32_t u[4]; } pk;
                pk.u[0] = pkbf(v0.x, v0.y); pk.u[1] = pkbf(v0.z, v0.w);
                pk.u[2] = pkbf(v1.x, v1.y); pk.u[3] = pkbf(v1.z, v1.w);
                a0 = pk.v;
            }
            {
                const float4 v0 = *(const float4*)(xr + 32768 + ko);   // tile 1: +64 rows
                const float4 v1 = *(const float4*)(xr + 32768 + ko + 4);
                union { bf16x8 v; uint32_t u[4]; } pk;
                pk.u[0] = pkbf(v0.x, v0.y); pk.u[1] = pkbf(v0.z, v0.w);
                pk.u[2] = pkbf(v1.x, v1.y); pk.u[3] = pkbf(v1.z, v1.w);
                a1 = pk.v;
            }
            #pragma unroll
            for (int nt = 0; nt < 8; ++nt) {
                const bf16x8 b = *(const bf16x8*)(bp + (size_t)nt * 8192 + ko);
                acc[0][nt] = __builtin_amdgcn_mfma_f32_16x16x32_bf16(a0, b, acc[0][nt], 0, 0, 0);
                acc[1][nt] = __builtin_amdgcn_mfma_f32_16x16x32_bf16(a1, b, acc[1][nt], 0, 0, 0);
            }
        }
    }

    // ---- per-tile: sigmoid -> gates LDS, tree -> A-frags, GEMM2, store
    float gbv[8];
    #pragma unroll
    for (int nt = 0; nt < 8; ++nt) {
        int col = 128 * wc + nt * 16 + l15;
        gbv[nt] = (col < 255) ? gb[col] : 0.0f;
    }

    for (int t = 0; t < 2; ++t) {
        __syncthreads();   // gates region free (previous tile's tree reads done)

        // phase 2: C/D layout col=lane&15, row=4q+reg
        #pragma unroll
        for (int nt = 0; nt < 8; ++nt) {
            const int col = 128 * wc + nt * 16 + l15;
            #pragma unroll
            for (int r = 0; r < 4; ++r) {
                const int rowl = 16 * wr + 4 * q + r;
                float v = acc[t][nt][r] + gbv[nt];
                gs[rowl * 258 + col] = 1.0f / (1.0f + __expf(-v));
            }
        }
        __syncthreads();

        // phase 3: leaf probs -> GEMM2 A-frags. A[m=lane&15][k=c*32+q*8+j], leaf l = k, group G = l>>3 = 4c+q
        const float* gr = gs + (16 * wr + l15) * 258;
        float g0v = gr[0];
        float t1v[2] = { g0v, 1.0f - g0v };
        float t2v[4], t3v[8];
        #pragma unroll
        for (int u = 0; u < 2; ++u) {
            float gl = gr[1 + u];
            t2v[2 * u] = t1v[u] * gl; t2v[2 * u + 1] = t1v[u] - t2v[2 * u];
        }
        #pragma unroll
        for (int u = 0; u < 4; ++u) {
            float gl = gr[3 + u];
            t3v[2 * u] = t2v[u] * gl; t3v[2 * u + 1] = t2v[u] - t3v[2 * u];
        }
        bf16x8 a2[8];
        #pragma unroll
        for (int c = 0; c < 8; ++c) {
            const int G = c * 4 + q;
            float p = t3v[c];
            float g3 = gr[7 + c];                    // level 3: node 7 + (G>>2), bit (G>>1)&1 = q>>1
            p = (q & 2) ? (p - p * g3) : (p * g3);
            float g4 = gr[15 + 2 * c + (q >> 1)];    // level 4: node 15 + (G>>1), bit G&1 = q&1
            p = (q & 1) ? (p - p * g4) : (p * g4);
            float g5 = gr[31 + G];
            float a0 = p * g5, a1 = p - a0;
            float g6a = gr[63 + 2 * G], g6b = gr[64 + 2 * G];
            float b00 = a0 * g6a, b01 = a0 - b00;
            float b10 = a1 * g6b, b11 = a1 - b10;
            float g70 = gr[127 + 4 * G], g71 = gr[128 + 4 * G];
            float g72 = gr[129 + 4 * G], g73 = gr[130 + 4 * G];
            float lf0 = b00 * g70, lf1 = b00 - lf0;
            float lf2 = b01 * g71, lf3 = b01 - lf2;
            float lf4 = b10 * g72, lf5 = b10 - lf4;
            float lf6 = b11 * g73, lf7 = b11 - lf6;
            union { bf16x8 v; uint32_t u[4]; } pk;
            pk.u[0] = pkbf(lf0, lf1);
            pk.u[1] = pkbf(lf2, lf3);
            pk.u[2] = pkbf(lf4, lf5);
            pk.u[3] = pkbf(lf6, lf7);
            a2[c] = pk.v;
        }

        // GEMM2: out_tile = leaf @ z^T, B-frags straight from L2-resident zb
        f32x4 acc2[8];
        #pragma unroll
        for (int i = 0; i < 8; ++i) acc2[i] = (f32x4){0.f, 0.f, 0.f, 0.f};
        #pragma unroll
        for (int nt = 0; nt < 8; ++nt) {
            const unsigned short* zrow = zb + (size_t)(128 * wc + nt * 16 + l15) * 256 + q * 8;
            #pragma unroll
            for (int c = 0; c < 8; ++c) {
                bf16x8 b = *(const bf16x8*)(zrow + c * 32);
                acc2[nt] = __builtin_amdgcn_mfma_f32_16x16x32_bf16(a2[c], b, acc2[nt], 0, 0, 0);
            }
        }

        // epilogue
        #pragma unroll
        for (int nt = 0; nt < 8; ++nt) {
            const int col = 128 * wc + nt * 16 + l15;
            #pragma unroll
            for (int r = 0; r < 4; ++r) {
                const int row = R0 + t * 64 + 16 * wr + 4 * q + r;
                out[(size_t)row * 256 + col] = acc2[nt][r];
            }
        }
    }
}

extern "C" void kernel_launch(void* const* d_in, const int* in_sizes, int n_in,
                              void* d_out, int out_size, void* d_ws, size_t ws_size,
                              hipStream_t stream) {
    const float* x  = (const float*)d_in[0];
    const float* gw = (const float*)d_in[1];
    const float* gb = (const float*)d_in[2];
    const float* z  = (const float*)d_in[3];
    float* outp = (float*)d_out;

    unsigned short* gwt = (unsigned short*)d_ws;     // 256*512 bf16 = 256 KB
    unsigned short* zbf = gwt + 256 * 512;           // 256*256 bf16 = 128 KB

    softtree_prep<<<96, 256, 0, stream>>>(gw, z, gwt, zbf);
    softtree_main<<<512, 512, 0, stream>>>(x, gb, gwt, zbf, outp);
}